// Round 1
// baseline (683.331 us; speedup 1.0000x reference)
//
#include <hip/hip_runtime.h>
#include <hip/hip_bf16.h>

// Problem constants: b=1, c=256, h=w=64 -> n=4096 pixels, 4 heads, hd=64,
// 32 groups of 8 channels. scale = hd^-0.5 = 0.125.
#define NPIX 4096
#define CCH  256
#define HD   64
#define NH   4
#define GSIZE 32768   // 8 channels * 4096 pixels per group (contiguous)

// ---------------------------------------------------------------------------
// Kernel 1: GroupNorm. One block per group (32 blocks). Group data contiguous.
// ---------------------------------------------------------------------------
__global__ __launch_bounds__(256) void gn_kernel(const float* __restrict__ X,
                                                 const float* __restrict__ gamma,
                                                 const float* __restrict__ beta,
                                                 float* __restrict__ Y)
{
    const int g = blockIdx.x;
    const int t = threadIdx.x;
    const float* Xg = X + g * GSIZE;
    float*       Yg = Y + g * GSIZE;

    float sum = 0.f, ssq = 0.f;
    for (int i = t * 4; i < GSIZE; i += 1024) {
        float4 v = *(const float4*)(Xg + i);
        sum += v.x + v.y + v.z + v.w;
        ssq += v.x * v.x + v.y * v.y + v.z * v.z + v.w * v.w;
    }
    #pragma unroll
    for (int off = 1; off < 64; off <<= 1) {
        sum += __shfl_xor(sum, off);
        ssq += __shfl_xor(ssq, off);
    }
    __shared__ float red[2][4];
    __shared__ float stats[2];
    const int wave = t >> 6;
    if ((t & 63) == 0) { red[0][wave] = sum; red[1][wave] = ssq; }
    __syncthreads();
    if (t == 0) {
        float s = red[0][0] + red[0][1] + red[0][2] + red[0][3];
        float q = red[1][0] + red[1][1] + red[1][2] + red[1][3];
        float mu  = s * (1.f / GSIZE);
        float var = q * (1.f / GSIZE) - mu * mu;
        stats[0] = mu;
        stats[1] = rsqrtf(var + 1e-6f);
    }
    __syncthreads();
    const float mu = stats[0], rs = stats[1];
    for (int i = t * 4; i < GSIZE; i += 1024) {
        float4 v = *(const float4*)(Xg + i);
        const int c = g * 8 + (i >> 12);       // i..i+3 same channel (4096-aligned)
        const float ga = gamma[c], be = beta[c];
        float4 y;
        y.x = (v.x - mu) * rs * ga + be;
        y.y = (v.y - mu) * rs * ga + be;
        y.z = (v.z - mu) * rs * ga + be;
        y.w = (v.w - mu) * rs * ga + be;
        *(float4*)(Yg + i) = y;
    }
}

// ---------------------------------------------------------------------------
// Kernel 2: fp32 GEMM  Y[256,4096] = W[256,256] @ X[256,4096] + bias (+ R).
// 64x64x16 tiles, 256 threads, 4x4 register micro-tile.
// ---------------------------------------------------------------------------
__global__ __launch_bounds__(256) void gemm256(const float* __restrict__ W,
                                               const float* __restrict__ X,
                                               const float* __restrict__ bias,
                                               const float* __restrict__ R,
                                               float* __restrict__ Y)
{
    __shared__ float As[16 * 68];   // As[k][m], pitch 68 (pad: bank spread + 16B align)
    __shared__ float Bs[16 * 64];   // Bs[k][n], pitch 64

    const int t  = threadIdx.x;
    const int tx = t & 15;          // n direction
    const int ty = t >> 4;          // m direction
    const int n0 = blockIdx.x * 64;
    const int m0 = blockIdx.y * 64;

    // staging coords
    const int lm  = t >> 2;          // 0..63 (A row)
    const int lk4 = (t & 3) * 4;     // A: 4 consecutive k
    const int bk  = t >> 4;          // 0..15 (B row)
    const int bn4 = (t & 15) * 4;

    float acc[4][4] = {};

    for (int k0 = 0; k0 < 256; k0 += 16) {
        __syncthreads();
        {
            float4 w4 = *(const float4*)(W + (m0 + lm) * 256 + k0 + lk4);
            As[(lk4 + 0) * 68 + lm] = w4.x;
            As[(lk4 + 1) * 68 + lm] = w4.y;
            As[(lk4 + 2) * 68 + lm] = w4.z;
            As[(lk4 + 3) * 68 + lm] = w4.w;
            *(float4*)(Bs + bk * 64 + bn4) =
                *(const float4*)(X + (k0 + bk) * NPIX + n0 + bn4);
        }
        __syncthreads();
        #pragma unroll
        for (int k = 0; k < 16; ++k) {
            float4 a4 = *(const float4*)(As + k * 68 + ty * 4);
            float4 b4 = *(const float4*)(Bs + k * 64 + tx * 4);
            acc[0][0] += a4.x * b4.x; acc[0][1] += a4.x * b4.y;
            acc[0][2] += a4.x * b4.z; acc[0][3] += a4.x * b4.w;
            acc[1][0] += a4.y * b4.x; acc[1][1] += a4.y * b4.y;
            acc[1][2] += a4.y * b4.z; acc[1][3] += a4.y * b4.w;
            acc[2][0] += a4.z * b4.x; acc[2][1] += a4.z * b4.y;
            acc[2][2] += a4.z * b4.z; acc[2][3] += a4.z * b4.w;
            acc[3][0] += a4.w * b4.x; acc[3][1] += a4.w * b4.y;
            acc[3][2] += a4.w * b4.z; acc[3][3] += a4.w * b4.w;
        }
    }

    #pragma unroll
    for (int i = 0; i < 4; ++i) {
        const int m = m0 + ty * 4 + i;
        const float bz = bias[m];
        float4 y;
        y.x = acc[i][0] + bz; y.y = acc[i][1] + bz;
        y.z = acc[i][2] + bz; y.w = acc[i][3] + bz;
        if (R) {
            float4 r4 = *(const float4*)(R + m * NPIX + n0 + tx * 4);
            y.x += r4.x; y.y += r4.y; y.z += r4.z; y.w += r4.w;
        }
        *(float4*)(Y + m * NPIX + n0 + tx * 4) = y;
    }
}

// ---------------------------------------------------------------------------
// Kernel 3: flash attention, fp32. One block = one head x 16 query rows.
// Q,K,V in [c=head*64+d][pixel] layout. Output written in the torch-faithful
// scrambled layout O[p*256 + head*64 + d] so the proj GEMM is plain.
// Thread t: row r = t>>4 (16 rows), 4-wide column slice c16 = t&15.
// ---------------------------------------------------------------------------
__global__ __launch_bounds__(256) void attn_kernel(const float* __restrict__ Q,
                                                   const float* __restrict__ K,
                                                   const float* __restrict__ V,
                                                   float* __restrict__ O)
{
    __shared__ float qt[16 * 65];   // qt[r][d] pitch 65
    __shared__ float kt[64 * 68];   // kt[d][mm] pitch 68
    __shared__ float vt[64 * 68];   // vt[mm][d] pitch 68
    __shared__ float pt[16 * 68];   // pt[r][mm] pitch 68

    const int t   = threadIdx.x;
    const int bid = blockIdx.x;
    // XCD swizzle: same head -> same XCD pair, K/V head (2MB) stays L2-resident
    const int head = (bid & 7) >> 1;
    const int tile = ((bid >> 3) << 1) | (bid & 1);
    const int p0   = tile * 16;

    const int r   = t >> 4;     // 0..15 query row within tile
    const int c16 = t & 15;     // 0..15 quad-column index

    const float* Kh = K + head * HD * NPIX;
    const float* Vh = V + head * HD * NPIX;

    // stage q tile
    for (int idx = t; idx < 16 * 64; idx += 256) {
        const int rr = idx & 15, d = idx >> 4;
        qt[rr * 65 + d] = Q[(head * HD + d) * NPIX + p0 + rr];
    }

    float m_r = -1e30f, l_r = 0.f;
    float4 o4 = {0.f, 0.f, 0.f, 0.f};

    for (int m0 = 0; m0 < NPIX; m0 += 64) {
        __syncthreads();   // waves done reading previous kt/vt (also covers qt)
        for (int idx = t; idx < 4096; idx += 256) {
            const int d = idx >> 6, mm = idx & 63;
            kt[d * 68 + mm] = Kh[d * NPIX + m0 + mm];
            vt[mm * 68 + d] = Vh[d * NPIX + m0 + mm];
        }
        __syncthreads();

        // ---- S = q . K^T (this thread: row r, columns c16*4 .. +3) ----
        float4 s4 = {0.f, 0.f, 0.f, 0.f};
        const float* ktp = kt + c16 * 4;
        const float* qtp = qt + r * 65;
        #pragma unroll 8
        for (int d = 0; d < 64; ++d) {
            const float qv = qtp[d];
            float4 k4 = *(const float4*)(ktp + d * 68);
            s4.x += qv * k4.x; s4.y += qv * k4.y;
            s4.z += qv * k4.z; s4.w += qv * k4.w;
        }
        s4.x *= 0.125f; s4.y *= 0.125f; s4.z *= 0.125f; s4.w *= 0.125f;

        // ---- online softmax (16 lanes per row) ----
        float tmax = fmaxf(fmaxf(s4.x, s4.y), fmaxf(s4.z, s4.w));
        #pragma unroll
        for (int off = 1; off < 16; off <<= 1)
            tmax = fmaxf(tmax, __shfl_xor(tmax, off, 16));
        const float new_m = fmaxf(m_r, tmax);
        const float alpha = __expf(m_r - new_m);
        float4 p4;
        p4.x = __expf(s4.x - new_m); p4.y = __expf(s4.y - new_m);
        p4.z = __expf(s4.z - new_m); p4.w = __expf(s4.w - new_m);
        float psum = p4.x + p4.y + p4.z + p4.w;
        #pragma unroll
        for (int off = 1; off < 16; off <<= 1)
            psum += __shfl_xor(psum, off, 16);
        l_r = l_r * alpha + psum;
        m_r = new_m;
        *(float4*)(pt + r * 68 + c16 * 4) = p4;
        o4.x *= alpha; o4.y *= alpha; o4.z *= alpha; o4.w *= alpha;

        __syncthreads();   // pt visible (safety; same-wave in practice)

        // ---- O += P @ V (this thread: row r, d = c16*4 .. +3) ----
        const float* vtp = vt + c16 * 4;
        const float* ptp = pt + r * 68;
        #pragma unroll 8
        for (int mm = 0; mm < 64; ++mm) {
            const float pv = ptp[mm];
            float4 v4 = *(const float4*)(vtp + mm * 68);
            o4.x += pv * v4.x; o4.y += pv * v4.y;
            o4.z += pv * v4.z; o4.w += pv * v4.w;
        }
    }

    const float inv = 1.f / l_r;
    o4.x *= inv; o4.y *= inv; o4.z *= inv; o4.w *= inv;
    // scrambled layout: L = p*256 + head*64 + d
    *(float4*)(O + (p0 + r) * 256 + head * HD + c16 * 4) = o4;
}

// ---------------------------------------------------------------------------
extern "C" void kernel_launch(void* const* d_in, const int* in_sizes, int n_in,
                              void* d_out, int out_size, void* d_ws, size_t ws_size,
                              hipStream_t stream)
{
    const float* x     = (const float*)d_in[0];
    const float* gamma = (const float*)d_in[1];
    const float* beta  = (const float*)d_in[2];
    const float* Wq    = (const float*)d_in[3];
    const float* bq    = (const float*)d_in[4];
    const float* Wk    = (const float*)d_in[5];
    const float* bk    = (const float*)d_in[6];
    const float* Wv    = (const float*)d_in[7];
    const float* bv    = (const float*)d_in[8];
    const float* Wp    = (const float*)d_in[9];
    const float* bp    = (const float*)d_in[10];
    float* out = (float*)d_out;

    float* ws = (float*)d_ws;
    float* hn = ws;                  // [256,4096] groupnorm output
    float* qb = ws + (1 << 20);      // [256,4096] q
    float* kb = ws + (2 << 20);      // [256,4096] k
    float* vb = ws + (3 << 20);      // [256,4096] v
    float* sb = ws + (4 << 20);      // [256,4096] scrambled attention out

    gn_kernel<<<32, 256, 0, stream>>>(x, gamma, beta, hn);

    dim3 gg(64, 4);  // N tiles x M tiles
    gemm256<<<gg, 256, 0, stream>>>(Wq, hn, bq, nullptr, qb);
    gemm256<<<gg, 256, 0, stream>>>(Wk, hn, bk, nullptr, kb);
    gemm256<<<gg, 256, 0, stream>>>(Wv, hn, bv, nullptr, vb);

    attn_kernel<<<1024, 256, 0, stream>>>(qb, kb, vb, sb);

    gemm256<<<gg, 256, 0, stream>>>(Wp, sb, bp, x, out);
}

// Round 2
// 294.638 us; speedup vs baseline: 2.3192x; 2.3192x over previous
//
#include <hip/hip_runtime.h>
#include <hip/hip_bf16.h>

// Problem constants: b=1, c=256, h=w=64 -> n=4096 pixels, 4 heads, hd=64,
// 32 groups of 8 channels. scale = hd^-0.5 = 0.125 (folded into Q convert).
#define NPIX 4096
#define CCH  256
#define HD   64
#define NH   4
#define GSIZE 32768   // 8 channels * 4096 pixels per group (contiguous)

typedef __bf16 bf16x8 __attribute__((ext_vector_type(8)));
typedef float  f32x4  __attribute__((ext_vector_type(4)));

#define PITCH 72   // bf16 LDS row pitch: 144 B = 36 dwords == 4 banks mod 32 -> <=2-way

// ---------------------------------------------------------------------------
// Kernel 1: GroupNorm. One block per group (32 blocks). Group data contiguous.
// ---------------------------------------------------------------------------
__global__ __launch_bounds__(256) void gn_kernel(const float* __restrict__ X,
                                                 const float* __restrict__ gamma,
                                                 const float* __restrict__ beta,
                                                 float* __restrict__ Y)
{
    const int g = blockIdx.x;
    const int t = threadIdx.x;
    const float* Xg = X + g * GSIZE;
    float*       Yg = Y + g * GSIZE;

    float sum = 0.f, ssq = 0.f;
    for (int i = t * 4; i < GSIZE; i += 1024) {
        float4 v = *(const float4*)(Xg + i);
        sum += v.x + v.y + v.z + v.w;
        ssq += v.x * v.x + v.y * v.y + v.z * v.z + v.w * v.w;
    }
    #pragma unroll
    for (int off = 1; off < 64; off <<= 1) {
        sum += __shfl_xor(sum, off);
        ssq += __shfl_xor(ssq, off);
    }
    __shared__ float red[2][4];
    __shared__ float stats[2];
    const int wave = t >> 6;
    if ((t & 63) == 0) { red[0][wave] = sum; red[1][wave] = ssq; }
    __syncthreads();
    if (t == 0) {
        float s = red[0][0] + red[0][1] + red[0][2] + red[0][3];
        float q = red[1][0] + red[1][1] + red[1][2] + red[1][3];
        float mu  = s * (1.f / GSIZE);
        float var = q * (1.f / GSIZE) - mu * mu;
        stats[0] = mu;
        stats[1] = rsqrtf(var + 1e-6f);
    }
    __syncthreads();
    const float mu = stats[0], rs = stats[1];
    for (int i = t * 4; i < GSIZE; i += 1024) {
        float4 v = *(const float4*)(Xg + i);
        const int c = g * 8 + (i >> 12);
        const float ga = gamma[c], be = beta[c];
        float4 y;
        y.x = (v.x - mu) * rs * ga + be;
        y.y = (v.y - mu) * rs * ga + be;
        y.z = (v.z - mu) * rs * ga + be;
        y.w = (v.w - mu) * rs * ga + be;
        *(float4*)(Yg + i) = y;
    }
}

// ---------------------------------------------------------------------------
// Kernel 2: fp32 GEMM  Y[256,4096] = W[256,256] @ X[256,4096] + bias (+ R).
// ---------------------------------------------------------------------------
__global__ __launch_bounds__(256) void gemm256(const float* __restrict__ W,
                                               const float* __restrict__ X,
                                               const float* __restrict__ bias,
                                               const float* __restrict__ R,
                                               float* __restrict__ Y)
{
    __shared__ float As[16 * 68];
    __shared__ float Bs[16 * 64];

    const int t  = threadIdx.x;
    const int tx = t & 15;
    const int ty = t >> 4;
    const int n0 = blockIdx.x * 64;
    const int m0 = blockIdx.y * 64;

    const int lm  = t >> 2;
    const int lk4 = (t & 3) * 4;
    const int bk  = t >> 4;
    const int bn4 = (t & 15) * 4;

    float acc[4][4] = {};

    for (int k0 = 0; k0 < 256; k0 += 16) {
        __syncthreads();
        {
            float4 w4 = *(const float4*)(W + (m0 + lm) * 256 + k0 + lk4);
            As[(lk4 + 0) * 68 + lm] = w4.x;
            As[(lk4 + 1) * 68 + lm] = w4.y;
            As[(lk4 + 2) * 68 + lm] = w4.z;
            As[(lk4 + 3) * 68 + lm] = w4.w;
            *(float4*)(Bs + bk * 64 + bn4) =
                *(const float4*)(X + (k0 + bk) * NPIX + n0 + bn4);
        }
        __syncthreads();
        #pragma unroll
        for (int k = 0; k < 16; ++k) {
            float4 a4 = *(const float4*)(As + k * 68 + ty * 4);
            float4 b4 = *(const float4*)(Bs + k * 64 + tx * 4);
            acc[0][0] += a4.x * b4.x; acc[0][1] += a4.x * b4.y;
            acc[0][2] += a4.x * b4.z; acc[0][3] += a4.x * b4.w;
            acc[1][0] += a4.y * b4.x; acc[1][1] += a4.y * b4.y;
            acc[1][2] += a4.y * b4.z; acc[1][3] += a4.y * b4.w;
            acc[2][0] += a4.z * b4.x; acc[2][1] += a4.z * b4.y;
            acc[2][2] += a4.z * b4.z; acc[2][3] += a4.z * b4.w;
            acc[3][0] += a4.w * b4.x; acc[3][1] += a4.w * b4.y;
            acc[3][2] += a4.w * b4.z; acc[3][3] += a4.w * b4.w;
        }
    }

    #pragma unroll
    for (int i = 0; i < 4; ++i) {
        const int m = m0 + ty * 4 + i;
        const float bz = bias[m];
        float4 y;
        y.x = acc[i][0] + bz; y.y = acc[i][1] + bz;
        y.z = acc[i][2] + bz; y.w = acc[i][3] + bz;
        if (R) {
            float4 r4 = *(const float4*)(R + m * NPIX + n0 + tx * 4);
            y.x += r4.x; y.y += r4.y; y.z += r4.z; y.w += r4.w;
        }
        *(float4*)(Y + m * NPIX + n0 + tx * 4) = y;
    }
}

// ---------------------------------------------------------------------------
// Kernel 3a: transpose+convert fp32 [256][4096] -> bf16 [head][pix][64]*scale
// One block per (head, 64-pix tile): 256 blocks.
// ---------------------------------------------------------------------------
__global__ __launch_bounds__(256) void convT(const float* __restrict__ X,
                                             __bf16* __restrict__ Y, float scale)
{
    __shared__ __bf16 tr[64 * PITCH];
    const int t    = threadIdx.x;
    const int head = blockIdx.x & 3;
    const int pix0 = (blockIdx.x >> 2) * 64;
    const int d  = t & 63;
    const int pg = t >> 6;     // pix group of 16

    const float* Xp = X + (head * 64 + d) * NPIX + pix0 + pg * 16;
    #pragma unroll
    for (int i = 0; i < 4; ++i) {
        float4 v = *(const float4*)(Xp + i * 4);
        const int px = pg * 16 + i * 4;
        tr[(px + 0) * PITCH + d] = (__bf16)(v.x * scale);
        tr[(px + 1) * PITCH + d] = (__bf16)(v.y * scale);
        tr[(px + 2) * PITCH + d] = (__bf16)(v.z * scale);
        tr[(px + 3) * PITCH + d] = (__bf16)(v.w * scale);
    }
    __syncthreads();
    const int px = t >> 2;
    const int dc = (t & 3) * 16;
    __bf16* Yp = Y + head * (NPIX * HD) + (pix0 + px) * HD + dc;
    *(bf16x8*)(Yp)     = *(const bf16x8*)(tr + px * PITCH + dc);
    *(bf16x8*)(Yp + 8) = *(const bf16x8*)(tr + px * PITCH + dc + 8);
}

// Kernel 3b: straight cast fp32 -> bf16 (V keeps [head][d][pix] layout)
__global__ __launch_bounds__(256) void convV(const float* __restrict__ X,
                                             __bf16* __restrict__ Y)
{
    const int i = (blockIdx.x * 256 + threadIdx.x) * 16;
    float4 a = *(const float4*)(X + i);
    float4 b = *(const float4*)(X + i + 4);
    float4 c = *(const float4*)(X + i + 8);
    float4 d = *(const float4*)(X + i + 12);
    bf16x8 lo = { (__bf16)a.x,(__bf16)a.y,(__bf16)a.z,(__bf16)a.w,
                  (__bf16)b.x,(__bf16)b.y,(__bf16)b.z,(__bf16)b.w };
    bf16x8 hi = { (__bf16)c.x,(__bf16)c.y,(__bf16)c.z,(__bf16)c.w,
                  (__bf16)d.x,(__bf16)d.y,(__bf16)d.z,(__bf16)d.w };
    *(bf16x8*)(Y + i)     = lo;
    *(bf16x8*)(Y + i + 8) = hi;
}

// ---------------------------------------------------------------------------
// Kernel 4: bf16 MFMA flash attention.
// Block = 1 head x 64 query rows, 4 waves x 16 rows. K-tiles of 64 keys.
// Q,K bf16 [head][pix][d] (Q pre-scaled by 0.125); V bf16 [head][d][pix].
// Output fp32 in torch-scrambled flat layout O[pix*256 + head*64 + d].
// MFMA 16x16x32 layouts (verified m89/m91/m120):
//   A[m=lane&15][k=quad*8+j]; B[k=quad*8+j][n=lane&15]; C: col=lane&15, row=quad*4+reg.
// ---------------------------------------------------------------------------
__global__ __launch_bounds__(256) void attn_mfma(const __bf16* __restrict__ Qb,
                                                 const __bf16* __restrict__ Kb,
                                                 const __bf16* __restrict__ Vb,
                                                 float* __restrict__ O)
{
    __shared__ __bf16 qt[64 * PITCH];     // [row][d]
    __shared__ __bf16 kt[64 * PITCH];     // [key][d]
    __shared__ __bf16 vt[64 * PITCH];     // [d][key]
    __shared__ __bf16 pt[4][16 * PITCH];  // per-wave [row16][key]

    const int t    = threadIdx.x;
    const int lane = t & 63;
    const int wave = t >> 6;
    const int l16  = lane & 15;
    const int quad = lane >> 4;

    const int head = blockIdx.x & 3;
    const int p0   = (blockIdx.x >> 2) * 64;

    const __bf16* Qh = Qb + head * (NPIX * HD);
    const __bf16* Kh = Kb + head * (NPIX * HD);
    const __bf16* Vh = Vb + head * (HD * NPIX);

    // stage Q tile (64 rows x 64 d) as 512 16B chunks
    for (int c = t; c < 512; c += 256) {
        const int row = c >> 3, dp = (c & 7) * 8;
        *(bf16x8*)(qt + row * PITCH + dp) =
            *(const bf16x8*)(Qh + (p0 + row) * HD + dp);
    }
    __syncthreads();

    const int myrow = wave * 16 + l16;
    const bf16x8 aq0 = *(const bf16x8*)(qt + myrow * PITCH + quad * 8);
    const bf16x8 aq1 = *(const bf16x8*)(qt + myrow * PITCH + 32 + quad * 8);

    f32x4 m_acc = {-1e30f, -1e30f, -1e30f, -1e30f};
    f32x4 l_acc = {0.f, 0.f, 0.f, 0.f};
    f32x4 o_acc[4] = {};

    __bf16* ptw = pt[wave];

    for (int m0 = 0; m0 < NPIX; m0 += 64) {
        __syncthreads();
        for (int c = t; c < 512; c += 256) {
            const int row = c >> 3, dp = (c & 7) * 8;
            *(bf16x8*)(kt + row * PITCH + dp) =
                *(const bf16x8*)(Kh + (m0 + row) * HD + dp);     // kt[key][d]
            *(bf16x8*)(vt + row * PITCH + dp) =
                *(const bf16x8*)(Vh + row * NPIX + m0 + dp);     // vt[d][key]
        }
        __syncthreads();

        // ---- S = Q K^T : 16 rows x 64 keys per wave ----
        f32x4 s[4] = {};
        #pragma unroll
        for (int nt = 0; nt < 4; ++nt) {
            bf16x8 b0 = *(const bf16x8*)(kt + (nt * 16 + l16) * PITCH + quad * 8);
            bf16x8 b1 = *(const bf16x8*)(kt + (nt * 16 + l16) * PITCH + 32 + quad * 8);
            s[nt] = __builtin_amdgcn_mfma_f32_16x16x32_bf16(aq0, b0, s[nt], 0, 0, 0);
            s[nt] = __builtin_amdgcn_mfma_f32_16x16x32_bf16(aq1, b1, s[nt], 0, 0, 0);
        }

        // ---- online softmax (rows = quad*4+reg; cols across 16 lanes of quad) ----
        f32x4 mx;
        #pragma unroll
        for (int r = 0; r < 4; ++r)
            mx[r] = fmaxf(fmaxf(s[0][r], s[1][r]), fmaxf(s[2][r], s[3][r]));
        #pragma unroll
        for (int off = 1; off < 16; off <<= 1) {
            #pragma unroll
            for (int r = 0; r < 4; ++r)
                mx[r] = fmaxf(mx[r], __shfl_xor(mx[r], off, 16));
        }
        f32x4 mnew, alpha;
        #pragma unroll
        for (int r = 0; r < 4; ++r) {
            mnew[r]  = fmaxf(m_acc[r], mx[r]);
            alpha[r] = __expf(m_acc[r] - mnew[r]);
        }
        f32x4 psum = {0.f, 0.f, 0.f, 0.f};
        #pragma unroll
        for (int nt = 0; nt < 4; ++nt) {
            #pragma unroll
            for (int r = 0; r < 4; ++r) {
                const float p = __expf(s[nt][r] - mnew[r]);
                psum[r] += p;
                ptw[(quad * 4 + r) * PITCH + nt * 16 + l16] = (__bf16)p;
            }
        }
        #pragma unroll
        for (int off = 1; off < 16; off <<= 1) {
            #pragma unroll
            for (int r = 0; r < 4; ++r)
                psum[r] += __shfl_xor(psum[r], off, 16);
        }
        #pragma unroll
        for (int r = 0; r < 4; ++r) {
            l_acc[r] = l_acc[r] * alpha[r] + psum[r];
            m_acc[r] = mnew[r];
        }
        #pragma unroll
        for (int nt = 0; nt < 4; ++nt) {
            o_acc[nt][0] *= alpha[0]; o_acc[nt][1] *= alpha[1];
            o_acc[nt][2] *= alpha[2]; o_acc[nt][3] *= alpha[3];
        }

        // ---- O += P V : P round-trips LDS (C-layout -> A-layout), per-wave tile ----
        const bf16x8 ap0 = *(const bf16x8*)(ptw + l16 * PITCH + quad * 8);
        const bf16x8 ap1 = *(const bf16x8*)(ptw + l16 * PITCH + 32 + quad * 8);
        #pragma unroll
        for (int nt = 0; nt < 4; ++nt) {
            bf16x8 bv0 = *(const bf16x8*)(vt + (nt * 16 + l16) * PITCH + quad * 8);
            bf16x8 bv1 = *(const bf16x8*)(vt + (nt * 16 + l16) * PITCH + 32 + quad * 8);
            o_acc[nt] = __builtin_amdgcn_mfma_f32_16x16x32_bf16(ap0, bv0, o_acc[nt], 0, 0, 0);
            o_acc[nt] = __builtin_amdgcn_mfma_f32_16x16x32_bf16(ap1, bv1, o_acc[nt], 0, 0, 0);
        }
    }

    f32x4 inv;
    #pragma unroll
    for (int r = 0; r < 4; ++r) inv[r] = 1.f / l_acc[r];
    const int rowbase = p0 + wave * 16 + quad * 4;
    #pragma unroll
    for (int r = 0; r < 4; ++r) {
        #pragma unroll
        for (int nt = 0; nt < 4; ++nt) {
            O[(rowbase + r) * CCH + head * HD + nt * 16 + l16] = o_acc[nt][r] * inv[r];
        }
    }
}

// ---------------------------------------------------------------------------
extern "C" void kernel_launch(void* const* d_in, const int* in_sizes, int n_in,
                              void* d_out, int out_size, void* d_ws, size_t ws_size,
                              hipStream_t stream)
{
    const float* x     = (const float*)d_in[0];
    const float* gamma = (const float*)d_in[1];
    const float* beta  = (const float*)d_in[2];
    const float* Wq    = (const float*)d_in[3];
    const float* bq    = (const float*)d_in[4];
    const float* Wk    = (const float*)d_in[5];
    const float* bk    = (const float*)d_in[6];
    const float* Wv    = (const float*)d_in[7];
    const float* bv    = (const float*)d_in[8];
    const float* Wp    = (const float*)d_in[9];
    const float* bp    = (const float*)d_in[10];
    float* out = (float*)d_out;

    float* ws = (float*)d_ws;
    float* hn = ws;                  // [0,   1M) floats: groupnorm out
    float* qb = ws + (1 << 20);      // [1M,  2M): q fp32
    float* kb = ws + (2 << 20);      // [2M,  3M): k fp32
    float* vb = ws + (3 << 20);      // [3M,  4M): v fp32
    float* sb = ws + (4 << 20);      // [4M,  5M): scrambled attn out fp32
    // bf16 overlays (deps are strictly sequential on `stream`):
    __bf16* Qbf = (__bf16*)ws;                   // overlays hn (done after QKV GEMMs)
    __bf16* Kbf = (__bf16*)(ws + (1 << 19));     // second half of hn region
    __bf16* Vbf = (__bf16*)(ws + (1 << 20));     // overlays qb (done after Q convert)

    gn_kernel<<<32, 256, 0, stream>>>(x, gamma, beta, hn);

    dim3 gg(64, 4);
    gemm256<<<gg, 256, 0, stream>>>(Wq, hn, bq, nullptr, qb);
    gemm256<<<gg, 256, 0, stream>>>(Wk, hn, bk, nullptr, kb);
    gemm256<<<gg, 256, 0, stream>>>(Wv, hn, bv, nullptr, vb);

    convT<<<256, 256, 0, stream>>>(qb, Qbf, 0.125f);   // scale folded into Q
    convT<<<256, 256, 0, stream>>>(kb, Kbf, 1.0f);
    convV<<<256, 256, 0, stream>>>(vb, Vbf);

    attn_mfma<<<256, 256, 0, stream>>>(Qbf, Kbf, Vbf, sb);

    gemm256<<<gg, 256, 0, stream>>>(Wp, sb, bp, x, out);
}

// Round 3
// 202.307 us; speedup vs baseline: 3.3777x; 1.4564x over previous
//
#include <hip/hip_runtime.h>
#include <hip/hip_bf16.h>

// Problem constants: b=1, c=256, h=w=64 -> n=4096 pixels, 4 heads, hd=64,
// 32 groups of 8 channels. scale = hd^-0.5 = 0.125 (folded into Q).
#define NPIX 4096
#define CCH  256
#define HD   64
#define NH   4
#define GSIZE 32768   // 8 channels * 4096 pixels per group (contiguous)

typedef __bf16 bf16x8 __attribute__((ext_vector_type(8)));
typedef __bf16 bf16x4 __attribute__((ext_vector_type(4)));
typedef float  f32x4  __attribute__((ext_vector_type(4)));

#define PITCH 72   // bf16 LDS pitch for P tiles: 144B = 36 dwords -> <=2-way

// ---------------------------------------------------------------------------
// Kernel 1: GroupNorm. One block per group (32 blocks). Group data contiguous.
// ---------------------------------------------------------------------------
__global__ __launch_bounds__(256) void gn_kernel(const float* __restrict__ X,
                                                 const float* __restrict__ gamma,
                                                 const float* __restrict__ beta,
                                                 float* __restrict__ Y)
{
    const int g = blockIdx.x;
    const int t = threadIdx.x;
    const float* Xg = X + g * GSIZE;
    float*       Yg = Y + g * GSIZE;

    float sum = 0.f, ssq = 0.f;
    for (int i = t * 4; i < GSIZE; i += 1024) {
        float4 v = *(const float4*)(Xg + i);
        sum += v.x + v.y + v.z + v.w;
        ssq += v.x * v.x + v.y * v.y + v.z * v.z + v.w * v.w;
    }
    #pragma unroll
    for (int off = 1; off < 64; off <<= 1) {
        sum += __shfl_xor(sum, off);
        ssq += __shfl_xor(ssq, off);
    }
    __shared__ float red[2][4];
    __shared__ float stats[2];
    const int wave = t >> 6;
    if ((t & 63) == 0) { red[0][wave] = sum; red[1][wave] = ssq; }
    __syncthreads();
    if (t == 0) {
        float s = red[0][0] + red[0][1] + red[0][2] + red[0][3];
        float q = red[1][0] + red[1][1] + red[1][2] + red[1][3];
        float mu  = s * (1.f / GSIZE);
        float var = q * (1.f / GSIZE) - mu * mu;
        stats[0] = mu;
        stats[1] = rsqrtf(var + 1e-6f);
    }
    __syncthreads();
    const float mu = stats[0], rs = stats[1];
    for (int i = t * 4; i < GSIZE; i += 1024) {
        float4 v = *(const float4*)(Xg + i);
        const int c = g * 8 + (i >> 12);
        const float ga = gamma[c], be = beta[c];
        float4 y;
        y.x = (v.x - mu) * rs * ga + be;
        y.y = (v.y - mu) * rs * ga + be;
        y.z = (v.z - mu) * rs * ga + be;
        y.w = (v.w - mu) * rs * ga + be;
        *(float4*)(Yg + i) = y;
    }
}

// ---------------------------------------------------------------------------
// Kernel 2: fused QKV GEMM. grid (64 n-tiles, 4 m-tiles(=heads), 3 z).
// fp32 math, bf16 epilogues:
//   z=0: Q -> bf16 [head][pix][d] * 0.125 (LDS transpose)
//   z=1: K -> bf16 [head][pix][d]         (LDS transpose)
//   z=2: V -> bf16 [c][pix]               (straight cast)
// ---------------------------------------------------------------------------
__global__ __launch_bounds__(256) void gemm_qkv(const float* __restrict__ Wq,
                                                const float* __restrict__ bq,
                                                const float* __restrict__ Wk,
                                                const float* __restrict__ bk,
                                                const float* __restrict__ Wv,
                                                const float* __restrict__ bv,
                                                const float* __restrict__ X,
                                                __bf16* __restrict__ Qb,
                                                __bf16* __restrict__ Kb,
                                                __bf16* __restrict__ Vb)
{
    __shared__ float  As[16 * 68];
    __shared__ float  Bs[16 * 64];
    __shared__ __bf16 tb[64 * 68];   // transpose staging (Q/K epilogue)

    const int z = blockIdx.z;
    const float* W    = (z == 0) ? Wq : (z == 1) ? Wk : Wv;
    const float* bias = (z == 0) ? bq : (z == 1) ? bk : bv;

    const int t  = threadIdx.x;
    const int tx = t & 15;
    const int ty = t >> 4;
    const int n0 = blockIdx.x * 64;
    const int m0 = blockIdx.y * 64;   // head = blockIdx.y

    const int lm  = t >> 2;
    const int lk4 = (t & 3) * 4;
    const int bk_ = t >> 4;
    const int bn4 = (t & 15) * 4;

    float acc[4][4] = {};

    for (int k0 = 0; k0 < 256; k0 += 16) {
        __syncthreads();
        {
            float4 w4 = *(const float4*)(W + (m0 + lm) * 256 + k0 + lk4);
            As[(lk4 + 0) * 68 + lm] = w4.x;
            As[(lk4 + 1) * 68 + lm] = w4.y;
            As[(lk4 + 2) * 68 + lm] = w4.z;
            As[(lk4 + 3) * 68 + lm] = w4.w;
            *(float4*)(Bs + bk_ * 64 + bn4) =
                *(const float4*)(X + (k0 + bk_) * NPIX + n0 + bn4);
        }
        __syncthreads();
        #pragma unroll
        for (int k = 0; k < 16; ++k) {
            float4 a4 = *(const float4*)(As + k * 68 + ty * 4);
            float4 b4 = *(const float4*)(Bs + k * 64 + tx * 4);
            acc[0][0] += a4.x * b4.x; acc[0][1] += a4.x * b4.y;
            acc[0][2] += a4.x * b4.z; acc[0][3] += a4.x * b4.w;
            acc[1][0] += a4.y * b4.x; acc[1][1] += a4.y * b4.y;
            acc[1][2] += a4.y * b4.z; acc[1][3] += a4.y * b4.w;
            acc[2][0] += a4.z * b4.x; acc[2][1] += a4.z * b4.y;
            acc[2][2] += a4.z * b4.z; acc[2][3] += a4.z * b4.w;
            acc[3][0] += a4.w * b4.x; acc[3][1] += a4.w * b4.y;
            acc[3][2] += a4.w * b4.z; acc[3][3] += a4.w * b4.w;
        }
    }

    if (z == 2) {
        // V: [c][pix] straight bf16
        #pragma unroll
        for (int i = 0; i < 4; ++i) {
            const int m = m0 + ty * 4 + i;
            const float bz = bias[m];
            bf16x4 o;
            o[0] = (__bf16)(acc[i][0] + bz); o[1] = (__bf16)(acc[i][1] + bz);
            o[2] = (__bf16)(acc[i][2] + bz); o[3] = (__bf16)(acc[i][3] + bz);
            *(bf16x4*)(Vb + m * NPIX + n0 + tx * 4) = o;
        }
    } else {
        // Q/K: transpose to [head][pix][d] via LDS
        const float scale = (z == 0) ? 0.125f : 1.0f;
        __bf16* Y = ((z == 0) ? Qb : Kb) + blockIdx.y * (NPIX * HD);
        #pragma unroll
        for (int i = 0; i < 4; ++i) {
            const float bz = bias[m0 + ty * 4 + i];
            #pragma unroll
            for (int j = 0; j < 4; ++j)
                tb[(tx * 4 + j) * 68 + ty * 4 + i] = (__bf16)((acc[i][j] + bz) * scale);
        }
        __syncthreads();
        for (int c2 = t; c2 < 512; c2 += 256) {
            const int px = c2 >> 3, dc = (c2 & 7) * 8;
            bf16x4 lo = *(const bf16x4*)(tb + px * 68 + dc);
            bf16x4 hi = *(const bf16x4*)(tb + px * 68 + dc + 4);
            *(bf16x4*)(Y + (n0 + px) * HD + dc)     = lo;
            *(bf16x4*)(Y + (n0 + px) * HD + dc + 4) = hi;
        }
    }
}

// ---------------------------------------------------------------------------
// Kernel 3: bf16 MFMA flash attention, occupancy-oriented.
// Block = 1 head x 32 q-rows, 4 waves. Wave w independently streams keys
// [w*1024, (w+1)*1024) in 64-key steps: NO barriers in the main loop.
// K/V fragments loaded directly from global (L2-resident per XCD).
// Per-wave online softmax; 4-way flash merge via LDS at the end.
// Q,K bf16 [head][pix][d] (Q pre-scaled); V bf16 [head][d][pix].
// Output fp32 scrambled: O[pix*256 + head*64 + d].
// ---------------------------------------------------------------------------
__global__ __launch_bounds__(256) void attn_mfma(const __bf16* __restrict__ Qb,
                                                 const __bf16* __restrict__ Kb,
                                                 const __bf16* __restrict__ Vb,
                                                 float* __restrict__ O)
{
    __shared__ __bf16 pt[4][32 * PITCH];      // per-wave P tile [row32][key64]
    __shared__ float  co[4][32][68];          // combine: per-wave O partials
    __shared__ float  cm[4][32], cl[4][32];   // combine: per-wave m, l

    const int t    = threadIdx.x;
    const int lane = t & 63;
    const int wave = t >> 6;
    const int l16  = lane & 15;
    const int quad = lane >> 4;

    const int bid  = blockIdx.x;
    // XCD swizzle: head fixed per XCD pair -> K/V (1MB/head) L2-resident
    const int head = (bid & 7) >> 1;
    const int tile = ((bid >> 3) << 1) | (bid & 1);   // 0..127
    const int p0   = tile * 32;

    const __bf16* Qh = Qb + head * (NPIX * HD);
    const __bf16* Kh = Kb + head * (NPIX * HD);
    const __bf16* Vh = Vb + head * (HD * NPIX);

    // Q A-fragments for rows p0 + rs*16 + l16 (2 row-sets of 16)
    bf16x8 aq[2][2];
    #pragma unroll
    for (int rs = 0; rs < 2; ++rs) {
        const __bf16* qp = Qh + (p0 + rs * 16 + l16) * HD + quad * 8;
        aq[rs][0] = *(const bf16x8*)(qp);
        aq[rs][1] = *(const bf16x8*)(qp + 32);
    }

    f32x4 m_acc[2], l_acc[2], o_acc[2][4];
    #pragma unroll
    for (int rs = 0; rs < 2; ++rs) {
        m_acc[rs] = f32x4{-1e30f, -1e30f, -1e30f, -1e30f};
        l_acc[rs] = f32x4{0.f, 0.f, 0.f, 0.f};
        #pragma unroll
        for (int nt = 0; nt < 4; ++nt) o_acc[rs][nt] = f32x4{0.f, 0.f, 0.f, 0.f};
    }

    __bf16* ptw = pt[wave];

    for (int it = 0; it < 16; ++it) {
        const int kb = wave * 1024 + it * 64;

        // ---- load K and V B-fragments from global (in flight together) ----
        bf16x8 k0[4], k1[4], v0[4], v1[4];
        #pragma unroll
        for (int nt = 0; nt < 4; ++nt) {
            const __bf16* kp = Kh + (kb + nt * 16 + l16) * HD + quad * 8;
            k0[nt] = *(const bf16x8*)(kp);
            k1[nt] = *(const bf16x8*)(kp + 32);
            const __bf16* vp = Vh + (nt * 16 + l16) * NPIX + kb + quad * 8;
            v0[nt] = *(const bf16x8*)(vp);
            v1[nt] = *(const bf16x8*)(vp + 32);
        }

        // ---- S = Q K^T : 32 rows x 64 keys ----
        f32x4 s[2][4] = {};
        #pragma unroll
        for (int rs = 0; rs < 2; ++rs) {
            #pragma unroll
            for (int nt = 0; nt < 4; ++nt) {
                s[rs][nt] = __builtin_amdgcn_mfma_f32_16x16x32_bf16(aq[rs][0], k0[nt], s[rs][nt], 0, 0, 0);
                s[rs][nt] = __builtin_amdgcn_mfma_f32_16x16x32_bf16(aq[rs][1], k1[nt], s[rs][nt], 0, 0, 0);
            }
        }

        // ---- per-wave online softmax ----
        #pragma unroll
        for (int rs = 0; rs < 2; ++rs) {
            f32x4 mx;
            #pragma unroll
            for (int r = 0; r < 4; ++r)
                mx[r] = fmaxf(fmaxf(s[rs][0][r], s[rs][1][r]),
                              fmaxf(s[rs][2][r], s[rs][3][r]));
            #pragma unroll
            for (int off = 1; off < 16; off <<= 1) {
                #pragma unroll
                for (int r = 0; r < 4; ++r)
                    mx[r] = fmaxf(mx[r], __shfl_xor(mx[r], off, 16));
            }
            f32x4 mnew, alpha;
            #pragma unroll
            for (int r = 0; r < 4; ++r) {
                mnew[r]  = fmaxf(m_acc[rs][r], mx[r]);
                alpha[r] = __expf(m_acc[rs][r] - mnew[r]);
            }
            f32x4 psum = {0.f, 0.f, 0.f, 0.f};
            #pragma unroll
            for (int nt = 0; nt < 4; ++nt) {
                #pragma unroll
                for (int r = 0; r < 4; ++r) {
                    const float p = __expf(s[rs][nt][r] - mnew[r]);
                    psum[r] += p;
                    ptw[(rs * 16 + quad * 4 + r) * PITCH + nt * 16 + l16] = (__bf16)p;
                }
            }
            #pragma unroll
            for (int off = 1; off < 16; off <<= 1) {
                #pragma unroll
                for (int r = 0; r < 4; ++r)
                    psum[r] += __shfl_xor(psum[r], off, 16);
            }
            #pragma unroll
            for (int r = 0; r < 4; ++r) {
                l_acc[rs][r] = l_acc[rs][r] * alpha[r] + psum[r];
                m_acc[rs][r] = mnew[r];
            }
            #pragma unroll
            for (int nt = 0; nt < 4; ++nt) {
                o_acc[rs][nt][0] *= alpha[0]; o_acc[rs][nt][1] *= alpha[1];
                o_acc[rs][nt][2] *= alpha[2]; o_acc[rs][nt][3] *= alpha[3];
            }
        }

        // ---- O += P V (P: LDS round-trip C->A layout, same wave, no barrier) ----
        bf16x8 ap[2][2];
        #pragma unroll
        for (int rs = 0; rs < 2; ++rs) {
            ap[rs][0] = *(const bf16x8*)(ptw + (rs * 16 + l16) * PITCH + quad * 8);
            ap[rs][1] = *(const bf16x8*)(ptw + (rs * 16 + l16) * PITCH + 32 + quad * 8);
        }
        #pragma unroll
        for (int nt = 0; nt < 4; ++nt) {
            #pragma unroll
            for (int rs = 0; rs < 2; ++rs) {
                o_acc[rs][nt] = __builtin_amdgcn_mfma_f32_16x16x32_bf16(ap[rs][0], v0[nt], o_acc[rs][nt], 0, 0, 0);
                o_acc[rs][nt] = __builtin_amdgcn_mfma_f32_16x16x32_bf16(ap[rs][1], v1[nt], o_acc[rs][nt], 0, 0, 0);
            }
        }
    }

    // ---- write per-wave partials, then 4-way flash merge ----
    #pragma unroll
    for (int rs = 0; rs < 2; ++rs) {
        #pragma unroll
        for (int r = 0; r < 4; ++r) {
            const int row = rs * 16 + quad * 4 + r;
            if (l16 == 0) { cm[wave][row] = m_acc[rs][r]; cl[wave][row] = l_acc[rs][r]; }
            #pragma unroll
            for (int nt = 0; nt < 4; ++nt)
                co[wave][row][nt * 16 + l16] = o_acc[rs][nt][r];
        }
    }
    __syncthreads();

    for (int idx = t; idx < 32 * HD; idx += 256) {
        const int row = idx >> 6, d = idx & 63;
        const float m0v = cm[0][row], m1v = cm[1][row];
        const float m2v = cm[2][row], m3v = cm[3][row];
        const float ms = fmaxf(fmaxf(m0v, m1v), fmaxf(m2v, m3v));
        const float e0 = __expf(m0v - ms), e1 = __expf(m1v - ms);
        const float e2 = __expf(m2v - ms), e3 = __expf(m3v - ms);
        const float l = e0 * cl[0][row] + e1 * cl[1][row] + e2 * cl[2][row] + e3 * cl[3][row];
        const float o = e0 * co[0][row][d] + e1 * co[1][row][d]
                      + e2 * co[2][row][d] + e3 * co[3][row][d];
        O[(p0 + row) * CCH + head * HD + d] = o / l;
    }
}

// ---------------------------------------------------------------------------
// Kernel 4: fp32 GEMM for projection: Y = Wp @ sb + bp + x (residual).
// ---------------------------------------------------------------------------
__global__ __launch_bounds__(256) void gemm256(const float* __restrict__ W,
                                               const float* __restrict__ X,
                                               const float* __restrict__ bias,
                                               const float* __restrict__ R,
                                               float* __restrict__ Y)
{
    __shared__ float As[16 * 68];
    __shared__ float Bs[16 * 64];

    const int t  = threadIdx.x;
    const int tx = t & 15;
    const int ty = t >> 4;
    const int n0 = blockIdx.x * 64;
    const int m0 = blockIdx.y * 64;

    const int lm  = t >> 2;
    const int lk4 = (t & 3) * 4;
    const int bk  = t >> 4;
    const int bn4 = (t & 15) * 4;

    float acc[4][4] = {};

    for (int k0 = 0; k0 < 256; k0 += 16) {
        __syncthreads();
        {
            float4 w4 = *(const float4*)(W + (m0 + lm) * 256 + k0 + lk4);
            As[(lk4 + 0) * 68 + lm] = w4.x;
            As[(lk4 + 1) * 68 + lm] = w4.y;
            As[(lk4 + 2) * 68 + lm] = w4.z;
            As[(lk4 + 3) * 68 + lm] = w4.w;
            *(float4*)(Bs + bk * 64 + bn4) =
                *(const float4*)(X + (k0 + bk) * NPIX + n0 + bn4);
        }
        __syncthreads();
        #pragma unroll
        for (int k = 0; k < 16; ++k) {
            float4 a4 = *(const float4*)(As + k * 68 + ty * 4);
            float4 b4 = *(const float4*)(Bs + k * 64 + tx * 4);
            acc[0][0] += a4.x * b4.x; acc[0][1] += a4.x * b4.y;
            acc[0][2] += a4.x * b4.z; acc[0][3] += a4.x * b4.w;
            acc[1][0] += a4.y * b4.x; acc[1][1] += a4.y * b4.y;
            acc[1][2] += a4.y * b4.z; acc[1][3] += a4.y * b4.w;
            acc[2][0] += a4.z * b4.x; acc[2][1] += a4.z * b4.y;
            acc[2][2] += a4.z * b4.z; acc[2][3] += a4.z * b4.w;
            acc[3][0] += a4.w * b4.x; acc[3][1] += a4.w * b4.y;
            acc[3][2] += a4.w * b4.z; acc[3][3] += a4.w * b4.w;
        }
    }

    #pragma unroll
    for (int i = 0; i < 4; ++i) {
        const int m = m0 + ty * 4 + i;
        const float bz = bias[m];
        float4 y;
        y.x = acc[i][0] + bz; y.y = acc[i][1] + bz;
        y.z = acc[i][2] + bz; y.w = acc[i][3] + bz;
        if (R) {
            float4 r4 = *(const float4*)(R + m * NPIX + n0 + tx * 4);
            y.x += r4.x; y.y += r4.y; y.z += r4.z; y.w += r4.w;
        }
        *(float4*)(Y + m * NPIX + n0 + tx * 4) = y;
    }
}

// ---------------------------------------------------------------------------
extern "C" void kernel_launch(void* const* d_in, const int* in_sizes, int n_in,
                              void* d_out, int out_size, void* d_ws, size_t ws_size,
                              hipStream_t stream)
{
    const float* x     = (const float*)d_in[0];
    const float* gamma = (const float*)d_in[1];
    const float* beta  = (const float*)d_in[2];
    const float* Wq    = (const float*)d_in[3];
    const float* bq    = (const float*)d_in[4];
    const float* Wk    = (const float*)d_in[5];
    const float* bk    = (const float*)d_in[6];
    const float* Wv    = (const float*)d_in[7];
    const float* bv    = (const float*)d_in[8];
    const float* Wp    = (const float*)d_in[9];
    const float* bp    = (const float*)d_in[10];
    float* out = (float*)d_out;

    char* ws = (char*)d_ws;
    float*  hn  = (float*)(ws);                      // [0, 4MB) fp32 [256][4096]
    __bf16* Qbf = (__bf16*)(ws + (4  << 20));        // 2MB bf16 [head][pix][64]
    __bf16* Kbf = (__bf16*)(ws + (6  << 20));        // 2MB bf16 [head][pix][64]
    __bf16* Vbf = (__bf16*)(ws + (8  << 20));        // 2MB bf16 [c][pix]
    float*  sb  = (float*)(ws + (10 << 20));         // 4MB fp32 scrambled attn out

    gn_kernel<<<32, 256, 0, stream>>>(x, gamma, beta, hn);

    dim3 gq(64, 4, 3);
    gemm_qkv<<<gq, 256, 0, stream>>>(Wq, bq, Wk, bk, Wv, bv, hn, Qbf, Kbf, Vbf);

    attn_mfma<<<512, 256, 0, stream>>>(Qbf, Kbf, Vbf, sb);

    dim3 gg(64, 4);
    gemm256<<<gg, 256, 0, stream>>>(Wp, sb, bp, x, out);
}

// Round 5
// 179.306 us; speedup vs baseline: 3.8110x; 1.1283x over previous
//
#include <hip/hip_runtime.h>
#include <hip/hip_bf16.h>

// b=1, c=256, h=w=64 -> n=4096 pixels, 4 heads, hd=64, 32 groups x 8 ch.
// scale = hd^-0.5 = 0.125, folded into Wq/bq at weight conversion.
#define NPIX 4096
#define CCH  256
#define HD   64
#define GSIZE 32768   // 8 ch * 4096 pix per group (contiguous)

typedef __bf16 bf16x8 __attribute__((ext_vector_type(8)));
typedef __bf16 bf16x4 __attribute__((ext_vector_type(4)));
typedef float  f32x4  __attribute__((ext_vector_type(4)));

#define PPITCH 72   // P-tile pitch (bf16)
#define CPITCH 68   // combine-tile pitch (f32)
#define BPITCH 264  // proj B-tile pitch (bf16): [p][c~] rows

// MFMA 16x16x32_bf16 layouts (verified m89/m91, used in R2/R3):
//   A[m=lane&15][k=quad*8+j]  (read 8 contig k from layout [m][k])
//   B[k=quad*8+j][n=lane&15]  (read 8 contig k from layout [n][k])
//   C/D: row m = quad*4+reg, col n = lane&15

// ---------------------------------------------------------------------------
// Kernel 1: GroupNorm -> bf16 X^T [pix][c]. One block per group (32 blocks).
// ---------------------------------------------------------------------------
__global__ __launch_bounds__(256) void gn_t(const float* __restrict__ X,
                                            const float* __restrict__ gamma,
                                            const float* __restrict__ beta,
                                            __bf16* __restrict__ Xb)
{
    const int g = blockIdx.x;
    const int t = threadIdx.x;
    const float* Xg = X + g * GSIZE;

    float sum = 0.f, ssq = 0.f;
    for (int i = t * 4; i < GSIZE; i += 1024) {
        float4 v = *(const float4*)(Xg + i);
        sum += v.x + v.y + v.z + v.w;
        ssq += v.x * v.x + v.y * v.y + v.z * v.z + v.w * v.w;
    }
    #pragma unroll
    for (int off = 1; off < 64; off <<= 1) {
        sum += __shfl_xor(sum, off);
        ssq += __shfl_xor(ssq, off);
    }
    __shared__ float red[2][4];
    __shared__ float stats[2];
    const int wv = t >> 6;
    if ((t & 63) == 0) { red[0][wv] = sum; red[1][wv] = ssq; }
    __syncthreads();
    if (t == 0) {
        float s = red[0][0] + red[0][1] + red[0][2] + red[0][3];
        float q = red[1][0] + red[1][1] + red[1][2] + red[1][3];
        float mu  = s * (1.f / GSIZE);
        float var = q * (1.f / GSIZE) - mu * mu;
        stats[0] = mu;
        stats[1] = rsqrtf(var + 1e-6f);
    }
    __syncthreads();
    const float mu = stats[0], rs = stats[1];

    float a[8], b2[8];
    #pragma unroll
    for (int c = 0; c < 8; ++c) {
        const float ga = gamma[g * 8 + c] * rs;
        a[c]  = ga;
        b2[c] = beta[g * 8 + c] - mu * ga;
    }

    // write bf16 [pix][256] columns g*8..g*8+7
    for (int i = 0; i < 4; ++i) {
        const int p = t * 4 + i * 1024;
        float v[8][4];
        #pragma unroll
        for (int c = 0; c < 8; ++c)
            *(float4*)v[c] = *(const float4*)(Xg + c * NPIX + p);
        #pragma unroll
        for (int j = 0; j < 4; ++j) {
            bf16x8 o;
            #pragma unroll
            for (int c = 0; c < 8; ++c)
                o[c] = (__bf16)(v[c][j] * a[c] + b2[c]);
            *(bf16x8*)(Xb + (p + j) * CCH + g * 8) = o;
        }
    }
}

// ---------------------------------------------------------------------------
// Kernel 2: weight convert fp32->bf16, [outc][c] kept. Wq scaled by 0.125.
// ---------------------------------------------------------------------------
__global__ __launch_bounds__(256) void wconv(const float* __restrict__ Wq,
                                             const float* __restrict__ Wk,
                                             const float* __restrict__ Wv,
                                             const float* __restrict__ Wp,
                                             __bf16* __restrict__ Wb)
{
    const int i = (blockIdx.x * 256 + threadIdx.x) * 4;   // grid 64 -> 65536 elems
    const float sc[4] = {0.125f, 1.f, 1.f, 1.f};
    const float* src[4] = {Wq, Wk, Wv, Wp};
    #pragma unroll
    for (int m = 0; m < 4; ++m) {
        float4 v = *(const float4*)(src[m] + i);
        bf16x4 o;
        o[0] = (__bf16)(v.x * sc[m]); o[1] = (__bf16)(v.y * sc[m]);
        o[2] = (__bf16)(v.z * sc[m]); o[3] = (__bf16)(v.w * sc[m]);
        *(bf16x4*)(Wb + m * 65536 + i) = o;
    }
}

// ---------------------------------------------------------------------------
// Kernel 3: fused QKV bf16 MFMA GEMM. grid (64 pixblk, 8 ocblk, 3 z), 256 thr.
// Wave = 16 pix x 32 outc, K=256 in 8 chunks. No LDS. Direct global frags.
//   z<2 (Q/K): A=W (m=outc), B=X (n=pix); C -> [head][pix][d] bf16x4 stores.
//   z=2 (V):   A=X (m=pix),  B=W (n=outc); C -> [c][pix]     bf16x4 stores.
// ---------------------------------------------------------------------------
__global__ __launch_bounds__(256) void gemm_qkv(const __bf16* __restrict__ Xb,
                                                const __bf16* __restrict__ Wb,
                                                const float* __restrict__ bq,
                                                const float* __restrict__ bk,
                                                const float* __restrict__ bv,
                                                __bf16* __restrict__ Qb,
                                                __bf16* __restrict__ Kb,
                                                __bf16* __restrict__ Vb)
{
    const int t = threadIdx.x, lane = t & 63, wave = t >> 6;
    const int l16 = lane & 15, quad = lane >> 4;
    const int z   = blockIdx.z;
    const int pw  = blockIdx.x * 64 + wave * 16;
    const int oc0 = blockIdx.y * 32;
    const __bf16* W    = Wb + z * 65536;
    const float*  bias = (z == 0) ? bq : (z == 1) ? bk : bv;

    const __bf16* xrow = Xb + (pw + l16) * CCH;

    f32x4 acc[2] = {};
    if (z < 2) {
        #pragma unroll
        for (int kc = 0; kc < 8; ++kc) {
            bf16x8 b = *(const bf16x8*)(xrow + kc * 32 + quad * 8);
            #pragma unroll
            for (int ot = 0; ot < 2; ++ot) {
                bf16x8 a = *(const bf16x8*)(W + (oc0 + ot * 16 + l16) * CCH + kc * 32 + quad * 8);
                acc[ot] = __builtin_amdgcn_mfma_f32_16x16x32_bf16(a, b, acc[ot], 0, 0, 0);
            }
        }
        const float qs = (z == 0) ? 0.125f : 1.0f;
        __bf16* dst = ((z == 0) ? Qb : Kb) + (blockIdx.y >> 1) * (NPIX * HD);
        const int dbase = (blockIdx.y & 1) * 32;
        #pragma unroll
        for (int ot = 0; ot < 2; ++ot) {
            float4 bz = *(const float4*)(bias + oc0 + ot * 16 + quad * 4);
            bf16x4 o;
            o[0] = (__bf16)(acc[ot][0] + bz.x * qs);
            o[1] = (__bf16)(acc[ot][1] + bz.y * qs);
            o[2] = (__bf16)(acc[ot][2] + bz.z * qs);
            o[3] = (__bf16)(acc[ot][3] + bz.w * qs);
            *(bf16x4*)(dst + (pw + l16) * HD + dbase + ot * 16 + quad * 4) = o;
        }
    } else {
        #pragma unroll
        for (int kc = 0; kc < 8; ++kc) {
            bf16x8 a = *(const bf16x8*)(xrow + kc * 32 + quad * 8);
            #pragma unroll
            for (int ot = 0; ot < 2; ++ot) {
                bf16x8 b = *(const bf16x8*)(W + (oc0 + ot * 16 + l16) * CCH + kc * 32 + quad * 8);
                acc[ot] = __builtin_amdgcn_mfma_f32_16x16x32_bf16(a, b, acc[ot], 0, 0, 0);
            }
        }
        #pragma unroll
        for (int ot = 0; ot < 2; ++ot) {
            const int oc = oc0 + ot * 16 + l16;
            const float bz = bias[oc];
            bf16x4 o;
            o[0] = (__bf16)(acc[ot][0] + bz); o[1] = (__bf16)(acc[ot][1] + bz);
            o[2] = (__bf16)(acc[ot][2] + bz); o[3] = (__bf16)(acc[ot][3] + bz);
            *(bf16x4*)(Vb + oc * NPIX + pw + quad * 4) = o;
        }
    }
}

// ---------------------------------------------------------------------------
// Kernel 4: bf16 MFMA attention, NO online softmax (scores bounded: |s|<~7,
// exp<~1e3, l<~1e4 -> fp32-safe), S^T orientation.
// Block = 1 head x 32 q-rows, 4 waves; wave w owns keys [w*1024,(w+1)*1024).
// No barriers in main loop. l via ones-MFMA (matrix pipe). Wave partials are
// PLAIN SUMS -> merge = add. Output bf16 flat F[pix*256 + head*64 + d]
// (the torch-scramble makes the proj consume F as In[c~][4096]).
// ---------------------------------------------------------------------------
__global__ __launch_bounds__(256) void attn_mfma(const __bf16* __restrict__ Qb,
                                                 const __bf16* __restrict__ Kb,
                                                 const __bf16* __restrict__ Vb,
                                                 __bf16* __restrict__ Sb)
{
    __shared__ __bf16 pt[4][32 * PPITCH];     // per-wave P [qrow32][key64]
    __shared__ float  co[4][32 * CPITCH];     // per-wave O^T partial [qrow][d]
    __shared__ float  cl[4][32];              // per-wave l partial

    const int t = threadIdx.x, lane = t & 63, wave = t >> 6;
    const int l16 = lane & 15, quad = lane >> 4;

    const int bid  = blockIdx.x;
    const int head = (bid & 7) >> 1;                   // XCD-pair pinning
    const int tile = ((bid >> 3) << 1) | (bid & 1);    // 0..127
    const int p0   = tile * 32;

    const __bf16* Qh = Qb + head * (NPIX * HD);
    const __bf16* Kh = Kb + head * (NPIX * HD);
    const __bf16* Vh = Vb + head * (HD * NPIX);

    // Q B-frags: B[k=d][n=qrow] from layout [qrow][d]
    bf16x8 bqf[2][2];
    #pragma unroll
    for (int rs = 0; rs < 2; ++rs) {
        const __bf16* qp = Qh + (p0 + rs * 16 + l16) * HD;
        bqf[rs][0] = *(const bf16x8*)(qp + quad * 8);
        bqf[rs][1] = *(const bf16x8*)(qp + 32 + quad * 8);
    }

    bf16x8 ones;
    #pragma unroll
    for (int j = 0; j < 8; ++j) ones[j] = (__bf16)1.0f;

    f32x4 l_acc[2] = {};
    f32x4 o_acc[4][2] = {};   // [dt][rs]

    __bf16* ptw = pt[wave];

    for (int it = 0; it < 16; ++it) {
        const int kb = wave * 1024 + it * 64;

        // ---- S^T = K Q^T : C (key=kt*16+quad*4+r, qrow=rs*16+l16) ----
        f32x4 st[4][2] = {};
        #pragma unroll
        for (int kt = 0; kt < 4; ++kt) {
            const __bf16* kp = Kh + (kb + kt * 16 + l16) * HD;
            bf16x8 a0 = *(const bf16x8*)(kp + quad * 8);
            bf16x8 a1 = *(const bf16x8*)(kp + 32 + quad * 8);
            #pragma unroll
            for (int rs = 0; rs < 2; ++rs) {
                st[kt][rs] = __builtin_amdgcn_mfma_f32_16x16x32_bf16(a0, bqf[rs][0], st[kt][rs], 0, 0, 0);
                st[kt][rs] = __builtin_amdgcn_mfma_f32_16x16x32_bf16(a1, bqf[rs][1], st[kt][rs], 0, 0, 0);
            }
        }

        // ---- P = exp(S^T), packed b64 writes: 4 contig keys per store ----
        #pragma unroll
        for (int kt = 0; kt < 4; ++kt) {
            #pragma unroll
            for (int rs = 0; rs < 2; ++rs) {
                bf16x4 p;
                p[0] = (__bf16)__expf(st[kt][rs][0]);
                p[1] = (__bf16)__expf(st[kt][rs][1]);
                p[2] = (__bf16)__expf(st[kt][rs][2]);
                p[3] = (__bf16)__expf(st[kt][rs][3]);
                *(bf16x4*)(ptw + (rs * 16 + l16) * PPITCH + kt * 16 + quad * 4) = p;
            }
        }

        // ---- P B-frags (same-wave LDS RAW, waitcnt only, no barrier) ----
        bf16x8 bp[2][2];
        #pragma unroll
        for (int rs = 0; rs < 2; ++rs) {
            bp[rs][0] = *(const bf16x8*)(ptw + (rs * 16 + l16) * PPITCH + quad * 8);
            bp[rs][1] = *(const bf16x8*)(ptw + (rs * 16 + l16) * PPITCH + 32 + quad * 8);
        }

        // ---- l += rowsum(P) on the matrix pipe (A = ones) ----
        #pragma unroll
        for (int rs = 0; rs < 2; ++rs) {
            l_acc[rs] = __builtin_amdgcn_mfma_f32_16x16x32_bf16(ones, bp[rs][0], l_acc[rs], 0, 0, 0);
            l_acc[rs] = __builtin_amdgcn_mfma_f32_16x16x32_bf16(ones, bp[rs][1], l_acc[rs], 0, 0, 0);
        }

        // ---- O^T += V^T P^T : C (d=dt*16+quad*4+r, qrow=rs*16+l16) ----
        #pragma unroll
        for (int dt = 0; dt < 4; ++dt) {
            const __bf16* vp = Vh + (dt * 16 + l16) * NPIX + kb;
            bf16x8 v0 = *(const bf16x8*)(vp + quad * 8);
            bf16x8 v1 = *(const bf16x8*)(vp + 32 + quad * 8);
            #pragma unroll
            for (int rs = 0; rs < 2; ++rs) {
                o_acc[dt][rs] = __builtin_amdgcn_mfma_f32_16x16x32_bf16(v0, bp[rs][0], o_acc[dt][rs], 0, 0, 0);
                o_acc[dt][rs] = __builtin_amdgcn_mfma_f32_16x16x32_bf16(v1, bp[rs][1], o_acc[dt][rs], 0, 0, 0);
            }
        }
    }

    // ---- wave partials (plain sums) -> LDS ----
    #pragma unroll
    for (int dt = 0; dt < 4; ++dt)
        #pragma unroll
        for (int rs = 0; rs < 2; ++rs)
            *(f32x4*)(&co[wave][(rs * 16 + l16) * CPITCH + dt * 16 + quad * 4]) = o_acc[dt][rs];
    if (quad == 0) {
        cl[wave][l16]      = l_acc[0][0];
        cl[wave][16 + l16] = l_acc[1][0];
    }
    __syncthreads();

    // ---- merge = sum over 4 waves, divide, store bf16 F-layout ----
    {
        const int row = t >> 3, dg = (t & 7) * 8;
        const float l = cl[0][row] + cl[1][row] + cl[2][row] + cl[3][row];
        const float inv = 1.f / l;
        f32x4 s0 = {}, s1 = {};
        #pragma unroll
        for (int w = 0; w < 4; ++w) {
            s0 += *(const f32x4*)(&co[w][row * CPITCH + dg]);
            s1 += *(const f32x4*)(&co[w][row * CPITCH + dg + 4]);
        }
        bf16x8 o;
        o[0] = (__bf16)(s0[0] * inv); o[1] = (__bf16)(s0[1] * inv);
        o[2] = (__bf16)(s0[2] * inv); o[3] = (__bf16)(s0[3] * inv);
        o[4] = (__bf16)(s1[0] * inv); o[5] = (__bf16)(s1[1] * inv);
        o[6] = (__bf16)(s1[2] * inv); o[7] = (__bf16)(s1[3] * inv);
        *(bf16x8*)(Sb + (p0 + row) * CCH + head * HD + dg) = o;
    }
}

// ---------------------------------------------------------------------------
// Kernel 5: proj bf16 MFMA GEMM + bias + residual, fp32 out [c][pix].
// FIX vs R4: the attention flat array F must be consumed as In[c~][4096]
// (torch scramble), i.e. k=c~ is the STRIDED dim. Stage the 64-pixel panel
// In[0:256][p0:p0+64] into LDS transposed (Bs[p][c~]) with coalesced 16B
// global reads, then A-frags (m=pix) from LDS rows, B-frags = Wp from global.
// grid (64 pixblk, 8 ocblk). Wave = 16 pix x 32 outc.
// C (pix=quad*4+r, outc=l16) -> f32x4 stores along pix.
// ---------------------------------------------------------------------------
__global__ __launch_bounds__(256) void gemm_proj(const __bf16* __restrict__ Sb,
                                                 const __bf16* __restrict__ Wpb,
                                                 const float* __restrict__ bias,
                                                 const float* __restrict__ X,
                                                 float* __restrict__ Out)
{
    __shared__ __bf16 Bs[64 * BPITCH];   // [p local 64][c~ 256]

    const int t = threadIdx.x, lane = t & 63, wave = t >> 6;
    const int l16 = lane & 15, quad = lane >> 4;
    const int p0  = blockIdx.x * 64;
    const int oc0 = blockIdx.y * 32;

    // stage In[c~][p0..p0+63] -> Bs[p][c~]; thread t owns channel c~ = t
    {
        #pragma unroll
        for (int pg = 0; pg < 8; ++pg) {
            bf16x8 v = *(const bf16x8*)(Sb + t * NPIX + p0 + pg * 8);
            #pragma unroll
            for (int j = 0; j < 8; ++j)
                Bs[(pg * 8 + j) * BPITCH + t] = v[j];
        }
    }
    __syncthreads();

    const int pw = wave * 16;   // this wave's 16 pixels within the tile
    f32x4 acc[2] = {};
    #pragma unroll
    for (int kc = 0; kc < 8; ++kc) {
        bf16x8 a = *(const bf16x8*)(Bs + (pw + l16) * BPITCH + kc * 32 + quad * 8);
        #pragma unroll
        for (int ot = 0; ot < 2; ++ot) {
            bf16x8 b = *(const bf16x8*)(Wpb + (oc0 + ot * 16 + l16) * CCH + kc * 32 + quad * 8);
            acc[ot] = __builtin_amdgcn_mfma_f32_16x16x32_bf16(a, b, acc[ot], 0, 0, 0);
        }
    }
    #pragma unroll
    for (int ot = 0; ot < 2; ++ot) {
        const int oc = oc0 + ot * 16 + l16;
        const float bz = bias[oc];
        const int p = p0 + pw + quad * 4;
        f32x4 r4 = *(const f32x4*)(X + oc * NPIX + p);
        f32x4 y;
        y[0] = acc[ot][0] + bz + r4[0];
        y[1] = acc[ot][1] + bz + r4[1];
        y[2] = acc[ot][2] + bz + r4[2];
        y[3] = acc[ot][3] + bz + r4[3];
        *(f32x4*)(Out + oc * NPIX + p) = y;
    }
}

// ---------------------------------------------------------------------------
extern "C" void kernel_launch(void* const* d_in, const int* in_sizes, int n_in,
                              void* d_out, int out_size, void* d_ws, size_t ws_size,
                              hipStream_t stream)
{
    const float* x     = (const float*)d_in[0];
    const float* gamma = (const float*)d_in[1];
    const float* beta  = (const float*)d_in[2];
    const float* Wq    = (const float*)d_in[3];
    const float* bq    = (const float*)d_in[4];
    const float* Wk    = (const float*)d_in[5];
    const float* bk    = (const float*)d_in[6];
    const float* Wv    = (const float*)d_in[7];
    const float* bv    = (const float*)d_in[8];
    const float* Wp    = (const float*)d_in[9];
    const float* bp    = (const float*)d_in[10];
    float* out = (float*)d_out;

    char* ws = (char*)d_ws;
    __bf16* Xb  = (__bf16*)(ws);               // 2MB bf16 [pix][256] (gn out, X^T)
    __bf16* Qb  = (__bf16*)(ws + (2  << 20));  // 2MB bf16 [head][pix][64]
    __bf16* Kb  = (__bf16*)(ws + (4  << 20));  // 2MB bf16 [head][pix][64]
    __bf16* Vb  = (__bf16*)(ws + (6  << 20));  // 2MB bf16 [c][pix]
    __bf16* Sb  = (__bf16*)(ws + (8  << 20));  // 2MB bf16 flat F (In[c~][4096] view)
    __bf16* Wb  = (__bf16*)(ws + (10 << 20));  // 512KB bf16 4x[256][256]

    gn_t<<<32, 256, 0, stream>>>(x, gamma, beta, Xb);
    wconv<<<64, 256, 0, stream>>>(Wq, Wk, Wv, Wp, Wb);

    dim3 gq(64, 8, 3);
    gemm_qkv<<<gq, 256, 0, stream>>>(Xb, Wb, bq, bk, bv, Qb, Kb, Vb);

    attn_mfma<<<512, 256, 0, stream>>>(Qb, Kb, Vb, Sb);

    dim3 gp(64, 8);
    gemm_proj<<<gp, 256, 0, stream>>>(Sb, Wb + 3 * 65536, bp, x, out);
}